// Round 5
// baseline (217.970 us; speedup 1.0000x reference)
//
#include <hip/hip_runtime.h>
#include <hip/hip_bf16.h>

#define Bq 4
#define Sq 2048
#define Dq 512
#define Hq 8
#define HDq 64
#define Pq 64

typedef __attribute__((ext_vector_type(8))) short short8;
typedef __attribute__((ext_vector_type(4))) float f32x4;

__device__ inline unsigned short f2bf(float f) {
  unsigned int u = __float_as_uint(f);
  unsigned int r = u + 0x7FFFu + ((u >> 16) & 1u);
  return (unsigned short)(r >> 16);
}
__device__ inline float bf2f(unsigned short s) {
  return __uint_as_float(((unsigned int)s) << 16);
}
__device__ inline short8 ld8f(const float* __restrict__ p) {
  const float4 a = *(const float4*)p;
  const float4 b = *(const float4*)(p + 4);
  short8 r;
  r[0] = (short)f2bf(a.x); r[1] = (short)f2bf(a.y); r[2] = (short)f2bf(a.z); r[3] = (short)f2bf(a.w);
  r[4] = (short)f2bf(b.x); r[5] = (short)f2bf(b.y); r[6] = (short)f2bf(b.z); r[7] = (short)f2bf(b.w);
  return r;
}

// ---------------- generic fp32 -> bf16 elementwise (8/thread) ----------------
__global__ __launch_bounds__(256) void cvtbf(const float* __restrict__ in,
                                             unsigned short* __restrict__ out, int n8) {
  int i = blockIdx.x * 256 + threadIdx.x;
  if (i < n8) *(short8*)&out[(size_t)i * 8] = ld8f(in + (size_t)i * 8);
}

// ---------------- weight convert + transpose: Wt[n][k] = bf16(W[k][n] * scale) ----------------
__global__ __launch_bounds__(256) void convW(const float* __restrict__ W,
                                             unsigned short* __restrict__ Wt, float scale) {
  __shared__ float tile[32][33];
  const int tx = threadIdx.x & 31, ty = threadIdx.x >> 5;  // 32 x 8
  const int n0 = blockIdx.x * 32, k0 = blockIdx.y * 32;
  for (int j = 0; j < 4; ++j)
    tile[ty + j * 8][tx] = W[(size_t)(k0 + ty + j * 8) * Dq + n0 + tx];
  __syncthreads();
  for (int j = 0; j < 4; ++j)
    Wt[(size_t)(n0 + ty + j * 8) * Dq + k0 + tx] = f2bf(tile[tx][ty + j * 8] * scale);
}

// ---------------- GEMM: C[8192x512] = A[8192x512] * W[512x512] ----------------
template <bool AF32, int ADD_RES, bool WT>
__global__ __launch_bounds__(256) void gemm512(const void* __restrict__ Ap,
                                               const unsigned short* __restrict__ Wt,
                                               unsigned short* __restrict__ Cb,
                                               const float* __restrict__ res,
                                               float* __restrict__ Cf) {
  __shared__ unsigned short Alds[64][72];
  __shared__ unsigned short Blds[64][72];
  const int tid = threadIdx.x;
  const int lane = tid & 63, wv = tid >> 6;
  const int wr = wv >> 1, wc = wv & 1;  // 2x2 waves, each 32x32
  const int l15 = lane & 15, lg = lane >> 4;
  const int row0 = blockIdx.x * 64, col0 = blockIdx.y * 64;
  f32x4 acc[2][2] = {};
  for (int k0 = 0; k0 < Dq; k0 += 64) {
    __syncthreads();
    for (int h = 0; h < 2; ++h) {
      int id = tid + h * 256;
      int r = id >> 3, c8 = (id & 7) * 8;
      if (AF32) {
        const float* ap = (const float*)Ap + (size_t)(row0 + r) * Dq + k0 + c8;
        float4 f0 = *(const float4*)ap;
        float4 f1 = *(const float4*)(ap + 4);
        ushort4 u0 = {f2bf(f0.x), f2bf(f0.y), f2bf(f0.z), f2bf(f0.w)};
        ushort4 u1 = {f2bf(f1.x), f2bf(f1.y), f2bf(f1.z), f2bf(f1.w)};
        *(ushort4*)&Alds[r][c8] = u0;
        *(ushort4*)&Alds[r][c8 + 4] = u1;
      } else {
        *(uint4*)&Alds[r][c8] =
            *(const uint4*)((const unsigned short*)Ap + (size_t)(row0 + r) * Dq + k0 + c8);
      }
      *(uint4*)&Blds[r][c8] = *(const uint4*)&Wt[(size_t)(col0 + r) * Dq + k0 + c8];
    }
    __syncthreads();
    short8 a[2][2], b[2][2];
    for (int mi = 0; mi < 2; ++mi)
      for (int kc = 0; kc < 2; ++kc)
        a[mi][kc] = *(const short8*)&Alds[wr * 32 + mi * 16 + l15][kc * 32 + lg * 8];
    for (int ni = 0; ni < 2; ++ni)
      for (int kc = 0; kc < 2; ++kc)
        b[ni][kc] = *(const short8*)&Blds[wc * 32 + ni * 16 + l15][kc * 32 + lg * 8];
    for (int mi = 0; mi < 2; ++mi)
      for (int ni = 0; ni < 2; ++ni) {
        acc[mi][ni] = __builtin_amdgcn_mfma_f32_16x16x32_bf16(a[mi][0], b[ni][0], acc[mi][ni], 0, 0, 0);
        acc[mi][ni] = __builtin_amdgcn_mfma_f32_16x16x32_bf16(a[mi][1], b[ni][1], acc[mi][ni], 0, 0, 0);
      }
  }
  const int orow = row0 + wr * 32 + lg * 4;
  const int ocol = col0 + wc * 32 + l15;
  if (WT) {
    const int bidx = orow >> 11;
    for (int mi = 0; mi < 2; ++mi)
      for (int ni = 0; ni < 2; ++ni) {
        int gc = ocol + ni * 16;
        int s = (orow + mi * 16) & (Sq - 1);
        ushort4 w = {f2bf(acc[mi][ni][0]), f2bf(acc[mi][ni][1]),
                     f2bf(acc[mi][ni][2]), f2bf(acc[mi][ni][3])};
        *(ushort4*)&Cb[((size_t)(bidx * Dq + gc)) * Sq + s] = w;
      }
  } else {
    for (int mi = 0; mi < 2; ++mi)
      for (int ni = 0; ni < 2; ++ni)
        for (int rr = 0; rr < 4; ++rr) {
          int gr = orow + mi * 16 + rr, gc = ocol + ni * 16;
          float v = acc[mi][ni][rr];
          if (ADD_RES)
            Cf[(size_t)gr * Dq + gc] = v + res[(size_t)gr * Dq + gc];
          else
            Cb[(size_t)gr * Dq + gc] = f2bf(v);
        }
  }
}

// ---------------- positional similarity row-sums only: invsum[b][q] = 1/sum_k exp(score) -------
__global__ __launch_bounds__(256) void possim(const unsigned short* __restrict__ qpe,
                                              const unsigned short* __restrict__ kpe,
                                              float* __restrict__ invsum) {
  __shared__ float wsum[4][16];
  const int tid = threadIdx.x, lane = tid & 63, wv = tid >> 6;
  const int l15 = lane & 15, lg = lane >> 4;
  const int b = blockIdx.y, q0 = blockIdx.x * 16;
  const unsigned short* qrow = qpe + ((size_t)(b * Sq + q0 + l15)) * Pq + lg * 8;
  short8 aq0 = *(const short8*)qrow;
  short8 aq1 = *(const short8*)(qrow + 32);
  float lsum[4] = {0.f, 0.f, 0.f, 0.f};
  for (int t = wv; t < Sq / 64; t += 4) {
    int k0 = t * 64;
    f32x4 sc[4] = {};
#pragma unroll
    for (int ng = 0; ng < 4; ++ng) {
      const unsigned short* krow = kpe + ((size_t)(b * Sq + k0 + ng * 16 + l15)) * Pq + lg * 8;
      short8 bk0 = *(const short8*)krow;
      short8 bk1 = *(const short8*)(krow + 32);
      sc[ng] = __builtin_amdgcn_mfma_f32_16x16x32_bf16(aq0, bk0, sc[ng], 0, 0, 0);
      sc[ng] = __builtin_amdgcn_mfma_f32_16x16x32_bf16(aq1, bk1, sc[ng], 0, 0, 0);
    }
#pragma unroll
    for (int ng = 0; ng < 4; ++ng) {
      lsum[0] += __expf(sc[ng][0]);
      lsum[1] += __expf(sc[ng][1]);
      lsum[2] += __expf(sc[ng][2]);
      lsum[3] += __expf(sc[ng][3]);
    }
  }
  for (int rr = 0; rr < 4; ++rr)
    for (int m = 1; m < 16; m <<= 1) lsum[rr] += __shfl_xor(lsum[rr], m, 64);
  if (l15 == 0)
    for (int rr = 0; rr < 4; ++rr) wsum[wv][lg * 4 + rr] = lsum[rr];
  __syncthreads();
  if (tid < 16) {
    float tot = wsum[0][tid] + wsum[1][tid] + wsum[2][tid] + wsum[3][tid];
    invsum[b * Sq + q0 + tid] = 1.0f / tot;
  }
}

// ---------------- attention: LDS-staged K/Vt/kpe, double-buffered, 1 barrier/tile ------------
// simi = exp(qpe.kpe^T) is recomputed in-kernel via MFMA (identical op order to possim,
// so scores match invsum bitwise). No 32MB simi tensor traffic.
__global__ __launch_bounds__(256) void attn(const unsigned short* __restrict__ Qb,
                                            const unsigned short* __restrict__ Kb,
                                            const unsigned short* __restrict__ VbT,
                                            const unsigned short* __restrict__ qpeb,
                                            const unsigned short* __restrict__ kpeb,
                                            const float* __restrict__ invsum,
                                            const int* __restrict__ mask,
                                            unsigned short* __restrict__ O) {
  __shared__ unsigned short Klds[2][64][72];
  __shared__ unsigned short Vlds[2][64][72];
  __shared__ unsigned short Elds[2][64][72];  // kpe tile
  __shared__ unsigned short Plds[4][16][72];
  const int tid = threadIdx.x, lane = tid & 63, wv = tid >> 6;
  const int l15 = lane & 15, lg = lane >> 4;
  const int q0 = blockIdx.x * 64, h = blockIdx.y, b = blockIdx.z;
  const int qw = q0 + wv * 16;
  // staging: thread covers rows sr and sr+32, 16B (8 bf16) at col sc8
  const int sr = tid >> 3, sc8 = (tid & 7) * 8;
  const unsigned short* Kg = Kb + ((size_t)(b * Sq + sr)) * Dq + h * HDq + sc8;   // +k0*Dq
  const unsigned short* Vg = VbT + ((size_t)(b * Dq + h * HDq + sr)) * Sq + sc8;  // +k0
  const unsigned short* Eg = kpeb + ((size_t)(b * Sq + sr)) * Pq + sc8;           // +k0*Pq

  const unsigned short* qp = Qb + ((size_t)(b * Sq + qw + l15)) * Dq + h * HDq + lg * 8;
  short8 aq0 = *(const short8*)qp;
  short8 aq1 = *(const short8*)(qp + 32);
  const unsigned short* pp = qpeb + ((size_t)(b * Sq + qw + l15)) * Pq + lg * 8;
  short8 ap0 = *(const short8*)pp;
  short8 ap1 = *(const short8*)(pp + 32);
  float inv[4];
#pragma unroll
  for (int rr = 0; rr < 4; ++rr) inv[rr] = invsum[b * Sq + qw + lg * 4 + rr];
  const int* Mbase = mask + b * Sq;

  // prologue: stage tile 0 (both halves) into buffer 0
  {
    *(uint4*)&Klds[0][sr][sc8] = *(const uint4*)Kg;
    *(uint4*)&Klds[0][sr + 32][sc8] = *(const uint4*)(Kg + (size_t)32 * Dq);
    *(uint4*)&Vlds[0][sr][sc8] = *(const uint4*)Vg;
    *(uint4*)&Vlds[0][sr + 32][sc8] = *(const uint4*)(Vg + (size_t)32 * Sq);
    *(uint4*)&Elds[0][sr][sc8] = *(const uint4*)Eg;
    *(uint4*)&Elds[0][sr + 32][sc8] = *(const uint4*)(Eg + (size_t)32 * Pq);
  }
  f32x4 oacc[4] = {};
  float lsum[4] = {0.f, 0.f, 0.f, 0.f};
  int cur = 0;
  for (int t = 0; t < Sq / 64; ++t) {
    const int k0 = t * 64;
    __syncthreads();
    uint4 nk0, nk1, nv0, nv1, ne0, ne1;
    const bool more = (t < Sq / 64 - 1);
    if (more) {
      nk0 = *(const uint4*)(Kg + (size_t)(k0 + 64) * Dq);
      nk1 = *(const uint4*)(Kg + (size_t)(k0 + 96) * Dq);
      nv0 = *(const uint4*)(Vg + (k0 + 64));
      nv1 = *(const uint4*)(Vg + (size_t)32 * Sq + (k0 + 64));
      ne0 = *(const uint4*)(Eg + (size_t)(k0 + 64) * Pq);
      ne1 = *(const uint4*)(Eg + (size_t)(k0 + 96) * Pq);
    }
    // QK^T (pre-scaled by 1/8 via Wq) and positional scores qpe.kpe^T
    f32x4 sc[4] = {};
    f32x4 sp[4] = {};
#pragma unroll
    for (int ng = 0; ng < 4; ++ng) {
      short8 bk0 = *(const short8*)&Klds[cur][ng * 16 + l15][lg * 8];
      short8 bk1 = *(const short8*)&Klds[cur][ng * 16 + l15][32 + lg * 8];
      sc[ng] = __builtin_amdgcn_mfma_f32_16x16x32_bf16(aq0, bk0, sc[ng], 0, 0, 0);
      sc[ng] = __builtin_amdgcn_mfma_f32_16x16x32_bf16(aq1, bk1, sc[ng], 0, 0, 0);
      short8 be0 = *(const short8*)&Elds[cur][ng * 16 + l15][lg * 8];
      short8 be1 = *(const short8*)&Elds[cur][ng * 16 + l15][32 + lg * 8];
      sp[ng] = __builtin_amdgcn_mfma_f32_16x16x32_bf16(ap0, be0, sp[ng], 0, 0, 0);
      sp[ng] = __builtin_amdgcn_mfma_f32_16x16x32_bf16(ap1, be1, sp[ng], 0, 0, 0);
    }
    // softmax numerator: p = exp(sc * exp(sp) * inv + mask_bias)
#pragma unroll
    for (int ng = 0; ng < 4; ++ng) {
      int kk = k0 + ng * 16 + l15;
      float ma = ((float)Mbase[kk] - 1.0f) * 1e8f;
#pragma unroll
      for (int rr = 0; rr < 4; ++rr) {
        float es = __expf(sp[ng][rr]);
        float p = __expf(fmaf(sc[ng][rr] * es, inv[rr], ma));
        lsum[rr] += p;
        Plds[wv][lg * 4 + rr][ng * 16 + l15] = f2bf(p);
      }
    }
    // P reload (per-wave LDS region; wave-internal ordering via lgkmcnt)
    short8 pa0 = *(const short8*)&Plds[wv][l15][lg * 8];
    short8 pa1 = *(const short8*)&Plds[wv][l15][32 + lg * 8];
#pragma unroll
    for (int dg = 0; dg < 4; ++dg) {
      short8 bv0 = *(const short8*)&Vlds[cur][dg * 16 + l15][lg * 8];
      short8 bv1 = *(const short8*)&Vlds[cur][dg * 16 + l15][32 + lg * 8];
      oacc[dg] = __builtin_amdgcn_mfma_f32_16x16x32_bf16(pa0, bv0, oacc[dg], 0, 0, 0);
      oacc[dg] = __builtin_amdgcn_mfma_f32_16x16x32_bf16(pa1, bv1, oacc[dg], 0, 0, 0);
    }
    // write next tile into the other buffer
    if (more) {
      *(uint4*)&Klds[cur ^ 1][sr][sc8] = nk0;
      *(uint4*)&Klds[cur ^ 1][sr + 32][sc8] = nk1;
      *(uint4*)&Vlds[cur ^ 1][sr][sc8] = nv0;
      *(uint4*)&Vlds[cur ^ 1][sr + 32][sc8] = nv1;
      *(uint4*)&Elds[cur ^ 1][sr][sc8] = ne0;
      *(uint4*)&Elds[cur ^ 1][sr + 32][sc8] = ne1;
      cur ^= 1;
    }
  }
#pragma unroll
  for (int rr = 0; rr < 4; ++rr)
    for (int m = 1; m < 16; m <<= 1) lsum[rr] += __shfl_xor(lsum[rr], m, 64);
#pragma unroll
  for (int dg = 0; dg < 4; ++dg)
    for (int rr = 0; rr < 4; ++rr) {
      int qg = qw + lg * 4 + rr;
      O[((size_t)(b * Sq + qg)) * Dq + h * HDq + dg * 16 + l15] = f2bf(oacc[dg][rr] / lsum[rr]);
    }
}

// ---------------- LayerNorm in-place on d_out ----------------
__global__ __launch_bounds__(256) void lnorm(float* __restrict__ X,
                                             const float* __restrict__ gamma,
                                             const float* __restrict__ beta) {
  const int tid = threadIdx.x, lane = tid & 63, wv = tid >> 6;
  const int row = blockIdx.x * 4 + wv;
  float* xr = X + (size_t)row * Dq + lane * 8;
  float4 x0 = *(float4*)xr;
  float4 x1 = *(float4*)(xr + 4);
  float s = x0.x + x0.y + x0.z + x0.w + x1.x + x1.y + x1.z + x1.w;
  float s2 = x0.x * x0.x + x0.y * x0.y + x0.z * x0.z + x0.w * x0.w +
             x1.x * x1.x + x1.y * x1.y + x1.z * x1.z + x1.w * x1.w;
  for (int m = 1; m < 64; m <<= 1) {
    s += __shfl_xor(s, m, 64);
    s2 += __shfl_xor(s2, m, 64);
  }
  float mu = s * (1.0f / 512.0f);
  float var = s2 * (1.0f / 512.0f) - mu * mu;
  float rstd = rsqrtf(var + 1e-5f);
  const float* g = gamma + lane * 8;
  const float* be = beta + lane * 8;
  float4 y0, y1;
  y0.x = (x0.x - mu) * rstd * g[0] + be[0];
  y0.y = (x0.y - mu) * rstd * g[1] + be[1];
  y0.z = (x0.z - mu) * rstd * g[2] + be[2];
  y0.w = (x0.w - mu) * rstd * g[3] + be[3];
  y1.x = (x1.x - mu) * rstd * g[4] + be[4];
  y1.y = (x1.y - mu) * rstd * g[5] + be[5];
  y1.z = (x1.z - mu) * rstd * g[6] + be[6];
  y1.w = (x1.w - mu) * rstd * g[7] + be[7];
  *(float4*)xr = y0;
  *(float4*)(xr + 4) = y1;
}

extern "C" void kernel_launch(void* const* d_in, const int* in_sizes, int n_in,
                              void* d_out, int out_size, void* d_ws, size_t ws_size,
                              hipStream_t stream) {
  const float* query = (const float*)d_in[0];
  const float* key = (const float*)d_in[1];
  const float* value = (const float*)d_in[2];
  const float* qpe = (const float*)d_in[3];
  const float* kpe = (const float*)d_in[4];
  const int* mask = (const int*)d_in[5];
  const float* Wq = (const float*)d_in[6];
  const float* Wk = (const float*)d_in[7];
  const float* Wv = (const float*)d_in[8];
  const float* Wo = (const float*)d_in[9];
  const float* gamma = (const float*)d_in[10];
  const float* beta = (const float*)d_in[11];
  float* out = (float*)d_out;

  char* ws = (char*)d_ws;
  size_t off = 0;
  unsigned short* Qb = (unsigned short*)(ws + off); off += (size_t)Bq * Sq * Dq * 2;    // 8MB
  unsigned short* Kb = (unsigned short*)(ws + off); off += (size_t)Bq * Sq * Dq * 2;    // 8MB
  unsigned short* VbT = (unsigned short*)(ws + off); off += (size_t)Bq * Sq * Dq * 2;   // 8MB
  unsigned short* Wqt = (unsigned short*)(ws + off); off += (size_t)Dq * Dq * 2;
  unsigned short* Wkt = (unsigned short*)(ws + off); off += (size_t)Dq * Dq * 2;
  unsigned short* Wvt = (unsigned short*)(ws + off); off += (size_t)Dq * Dq * 2;
  unsigned short* Wot = (unsigned short*)(ws + off); off += (size_t)Dq * Dq * 2;
  float* invsum = (float*)(ws + off); off += (size_t)Bq * Sq * 4;
  unsigned short* Ob = (unsigned short*)(ws + off); off += (size_t)Bq * Sq * Dq * 2;    // 8MB
  unsigned short* qpeb = (unsigned short*)(ws + off); off += (size_t)Bq * Sq * Pq * 2;  // 1MB
  unsigned short* kpeb = (unsigned short*)(ws + off); off += (size_t)Bq * Sq * Pq * 2;  // 1MB

  dim3 blk(256);
  convW<<<dim3(16, 16), blk, 0, stream>>>(Wq, Wqt, 0.125f);  // fold 1/sqrt(HD) into Wq
  convW<<<dim3(16, 16), blk, 0, stream>>>(Wk, Wkt, 1.0f);
  convW<<<dim3(16, 16), blk, 0, stream>>>(Wv, Wvt, 1.0f);
  convW<<<dim3(16, 16), blk, 0, stream>>>(Wo, Wot, 1.0f);
  cvtbf<<<dim3(Bq * Sq * Pq / 8 / 256), blk, 0, stream>>>(qpe, qpeb, Bq * Sq * Pq / 8);
  cvtbf<<<dim3(Bq * Sq * Pq / 8 / 256), blk, 0, stream>>>(kpe, kpeb, Bq * Sq * Pq / 8);
  possim<<<dim3(Sq / 16, Bq), blk, 0, stream>>>(qpeb, kpeb, invsum);
  gemm512<true, 0, false><<<dim3(128, 8), blk, 0, stream>>>(query, Wqt, Qb, nullptr, nullptr);
  gemm512<true, 0, false><<<dim3(128, 8), blk, 0, stream>>>(key, Wkt, Kb, nullptr, nullptr);
  gemm512<true, 0, true><<<dim3(128, 8), blk, 0, stream>>>(value, Wvt, VbT, nullptr, nullptr);
  attn<<<dim3(Sq / 64, Hq, Bq), blk, 0, stream>>>(Qb, Kb, VbT, qpeb, kpeb, invsum, mask, Ob);
  gemm512<false, 1, false><<<dim3(128, 8), blk, 0, stream>>>(Ob, Wot, nullptr, query, out);
  lnorm<<<dim3(Bq * Sq / 4), blk, 0, stream>>>(out, gamma, beta);
}

// Round 6
// 192.527 us; speedup vs baseline: 1.1322x; 1.1322x over previous
//
#include <hip/hip_runtime.h>
#include <hip/hip_bf16.h>

#define Bq 4
#define Sq 2048
#define Dq 512
#define Hq 8
#define HDq 64
#define Pq 64

typedef __attribute__((ext_vector_type(8))) short short8;
typedef __attribute__((ext_vector_type(4))) float f32x4;

__device__ inline unsigned short f2bf(float f) {
  unsigned int u = __float_as_uint(f);
  unsigned int r = u + 0x7FFFu + ((u >> 16) & 1u);
  return (unsigned short)(r >> 16);
}
__device__ inline float bf2f(unsigned short s) {
  return __uint_as_float(((unsigned int)s) << 16);
}
__device__ inline short8 ld8f(const float* __restrict__ p) {
  const float4 a = *(const float4*)p;
  const float4 b = *(const float4*)(p + 4);
  short8 r;
  r[0] = (short)f2bf(a.x); r[1] = (short)f2bf(a.y); r[2] = (short)f2bf(a.z); r[3] = (short)f2bf(a.w);
  r[4] = (short)f2bf(b.x); r[5] = (short)f2bf(b.y); r[6] = (short)f2bf(b.z); r[7] = (short)f2bf(b.w);
  return r;
}

// ---------------- generic fp32 -> bf16 elementwise (8/thread) ----------------
__global__ __launch_bounds__(256) void cvtbf(const float* __restrict__ in,
                                             unsigned short* __restrict__ out, int n8) {
  int i = blockIdx.x * 256 + threadIdx.x;
  if (i < n8) *(short8*)&out[(size_t)i * 8] = ld8f(in + (size_t)i * 8);
}

// ---------------- weight convert + transpose: Wt[n][k] = bf16(W[k][n] * scale) ----------------
__global__ __launch_bounds__(256) void convW(const float* __restrict__ W,
                                             unsigned short* __restrict__ Wt, float scale) {
  __shared__ float tile[32][33];
  const int tx = threadIdx.x & 31, ty = threadIdx.x >> 5;  // 32 x 8
  const int n0 = blockIdx.x * 32, k0 = blockIdx.y * 32;
  for (int j = 0; j < 4; ++j)
    tile[ty + j * 8][tx] = W[(size_t)(k0 + ty + j * 8) * Dq + n0 + tx];
  __syncthreads();
  for (int j = 0; j < 4; ++j)
    Wt[(size_t)(n0 + ty + j * 8) * Dq + k0 + tx] = f2bf(tile[tx][ty + j * 8] * scale);
}

// ---------------- GEMM: C[8192x512] = A[8192x512] * W[512x512] ----------------
template <bool AF32, int ADD_RES, bool WT>
__global__ __launch_bounds__(256) void gemm512(const void* __restrict__ Ap,
                                               const unsigned short* __restrict__ Wt,
                                               unsigned short* __restrict__ Cb,
                                               const float* __restrict__ res,
                                               float* __restrict__ Cf) {
  __shared__ unsigned short Alds[64][72];
  __shared__ unsigned short Blds[64][72];
  const int tid = threadIdx.x;
  const int lane = tid & 63, wv = tid >> 6;
  const int wr = wv >> 1, wc = wv & 1;  // 2x2 waves, each 32x32
  const int l15 = lane & 15, lg = lane >> 4;
  const int row0 = blockIdx.x * 64, col0 = blockIdx.y * 64;
  f32x4 acc[2][2] = {};
  for (int k0 = 0; k0 < Dq; k0 += 64) {
    __syncthreads();
    for (int h = 0; h < 2; ++h) {
      int id = tid + h * 256;
      int r = id >> 3, c8 = (id & 7) * 8;
      if (AF32) {
        const float* ap = (const float*)Ap + (size_t)(row0 + r) * Dq + k0 + c8;
        float4 f0 = *(const float4*)ap;
        float4 f1 = *(const float4*)(ap + 4);
        ushort4 u0 = {f2bf(f0.x), f2bf(f0.y), f2bf(f0.z), f2bf(f0.w)};
        ushort4 u1 = {f2bf(f1.x), f2bf(f1.y), f2bf(f1.z), f2bf(f1.w)};
        *(ushort4*)&Alds[r][c8] = u0;
        *(ushort4*)&Alds[r][c8 + 4] = u1;
      } else {
        *(uint4*)&Alds[r][c8] =
            *(const uint4*)((const unsigned short*)Ap + (size_t)(row0 + r) * Dq + k0 + c8);
      }
      *(uint4*)&Blds[r][c8] = *(const uint4*)&Wt[(size_t)(col0 + r) * Dq + k0 + c8];
    }
    __syncthreads();
    short8 a[2][2], b[2][2];
    for (int mi = 0; mi < 2; ++mi)
      for (int kc = 0; kc < 2; ++kc)
        a[mi][kc] = *(const short8*)&Alds[wr * 32 + mi * 16 + l15][kc * 32 + lg * 8];
    for (int ni = 0; ni < 2; ++ni)
      for (int kc = 0; kc < 2; ++kc)
        b[ni][kc] = *(const short8*)&Blds[wc * 32 + ni * 16 + l15][kc * 32 + lg * 8];
    for (int mi = 0; mi < 2; ++mi)
      for (int ni = 0; ni < 2; ++ni) {
        acc[mi][ni] = __builtin_amdgcn_mfma_f32_16x16x32_bf16(a[mi][0], b[ni][0], acc[mi][ni], 0, 0, 0);
        acc[mi][ni] = __builtin_amdgcn_mfma_f32_16x16x32_bf16(a[mi][1], b[ni][1], acc[mi][ni], 0, 0, 0);
      }
  }
  const int orow = row0 + wr * 32 + lg * 4;
  const int ocol = col0 + wc * 32 + l15;
  if (WT) {
    const int bidx = orow >> 11;
    for (int mi = 0; mi < 2; ++mi)
      for (int ni = 0; ni < 2; ++ni) {
        int gc = ocol + ni * 16;
        int s = (orow + mi * 16) & (Sq - 1);
        ushort4 w = {f2bf(acc[mi][ni][0]), f2bf(acc[mi][ni][1]),
                     f2bf(acc[mi][ni][2]), f2bf(acc[mi][ni][3])};
        *(ushort4*)&Cb[((size_t)(bidx * Dq + gc)) * Sq + s] = w;
      }
  } else {
    for (int mi = 0; mi < 2; ++mi)
      for (int ni = 0; ni < 2; ++ni)
        for (int rr = 0; rr < 4; ++rr) {
          int gr = orow + mi * 16 + rr, gc = ocol + ni * 16;
          float v = acc[mi][ni][rr];
          if (ADD_RES)
            Cf[(size_t)gr * Dq + gc] = v + res[(size_t)gr * Dq + gc];
          else
            Cb[(size_t)gr * Dq + gc] = f2bf(v);
        }
  }
}

// ---------------- positional similarity ----------------
// Stores unnormalized exp in FRAGMENT-BLOCKED layout simiB[b][q/16][k][q%16] (bf16)
// so attn's reads are fully coalesced, plus invsum[b][q] = 1/rowsum.
__global__ __launch_bounds__(256) void possim(const unsigned short* __restrict__ qpe,
                                              const unsigned short* __restrict__ kpe,
                                              unsigned short* __restrict__ simiB,
                                              float* __restrict__ invsum) {
  __shared__ float wsum[4][16];
  const int tid = threadIdx.x, lane = tid & 63, wv = tid >> 6;
  const int l15 = lane & 15, lg = lane >> 4;
  const int b = blockIdx.y, q0 = blockIdx.x * 16;
  const unsigned short* qrow = qpe + ((size_t)(b * Sq + q0 + l15)) * Pq + lg * 8;
  short8 aq0 = *(const short8*)qrow;
  short8 aq1 = *(const short8*)(qrow + 32);
  unsigned short* sB = simiB + ((size_t)(b * (Sq / 16) + blockIdx.x)) * Sq * 16;
  float lsum[4] = {0.f, 0.f, 0.f, 0.f};
  for (int t = wv; t < Sq / 64; t += 4) {
    int k0 = t * 64;
    f32x4 sc[4] = {};
#pragma unroll
    for (int ng = 0; ng < 4; ++ng) {
      const unsigned short* krow = kpe + ((size_t)(b * Sq + k0 + ng * 16 + l15)) * Pq + lg * 8;
      short8 bk0 = *(const short8*)krow;
      short8 bk1 = *(const short8*)(krow + 32);
      sc[ng] = __builtin_amdgcn_mfma_f32_16x16x32_bf16(aq0, bk0, sc[ng], 0, 0, 0);
      sc[ng] = __builtin_amdgcn_mfma_f32_16x16x32_bf16(aq1, bk1, sc[ng], 0, 0, 0);
    }
#pragma unroll
    for (int ng = 0; ng < 4; ++ng) {
      float e0 = __expf(sc[ng][0]);
      float e1 = __expf(sc[ng][1]);
      float e2 = __expf(sc[ng][2]);
      float e3 = __expf(sc[ng][3]);
      lsum[0] += e0; lsum[1] += e1; lsum[2] += e2; lsum[3] += e3;
      ushort4 st = {f2bf(e0), f2bf(e1), f2bf(e2), f2bf(e3)};
      *(ushort4*)&sB[(size_t)(k0 + ng * 16 + l15) * 16 + lg * 4] = st;
    }
  }
  for (int rr = 0; rr < 4; ++rr)
    for (int m = 1; m < 16; m <<= 1) lsum[rr] += __shfl_xor(lsum[rr], m, 64);
  if (l15 == 0)
    for (int rr = 0; rr < 4; ++rr) wsum[wv][lg * 4 + rr] = lsum[rr];
  __syncthreads();
  if (tid < 16) {
    float tot = wsum[0][tid] + wsum[1][tid] + wsum[2][tid] + wsum[3][tid];
    invsum[b * Sq + q0 + tid] = 1.0f / tot;
  }
}

// ---------------- attention: LDS-staged K/Vt, double-buffered, 1 barrier/tile ----------------
// simi read from fragment-blocked simiB: per ng one coalesced 512B wave transaction.
__global__ __launch_bounds__(256) void attn(const unsigned short* __restrict__ Qb,
                                            const unsigned short* __restrict__ Kb,
                                            const unsigned short* __restrict__ VbT,
                                            const unsigned short* __restrict__ simiB,
                                            const float* __restrict__ invsum,
                                            const int* __restrict__ mask,
                                            unsigned short* __restrict__ O) {
  __shared__ unsigned short Klds[2][64][72];
  __shared__ unsigned short Vlds[2][64][72];
  __shared__ unsigned short Plds[4][16][72];
  const int tid = threadIdx.x, lane = tid & 63, wv = tid >> 6;
  const int l15 = lane & 15, lg = lane >> 4;
  const int q0 = blockIdx.x * 64, h = blockIdx.y, b = blockIdx.z;
  const int qw = q0 + wv * 16;
  // staging: thread covers rows sr and sr+32, 16B (8 bf16) at col sc8
  const int sr = tid >> 3, sc8 = (tid & 7) * 8;
  const unsigned short* Kg = Kb + ((size_t)(b * Sq + sr)) * Dq + h * HDq + sc8;   // +k0*Dq
  const unsigned short* Vg = VbT + ((size_t)(b * Dq + h * HDq + sr)) * Sq + sc8;  // +k0

  const unsigned short* qp = Qb + ((size_t)(b * Sq + qw + l15)) * Dq + h * HDq + lg * 8;
  short8 aq0 = *(const short8*)qp;
  short8 aq1 = *(const short8*)(qp + 32);
  float inv[4];
#pragma unroll
  for (int rr = 0; rr < 4; ++rr) inv[rr] = invsum[b * Sq + qw + lg * 4 + rr];
  // fragment-blocked simi: this wave's q-block index is blockIdx.x*4 + wv
  const unsigned short* sB =
      simiB + ((size_t)(b * (Sq / 16) + blockIdx.x * 4 + wv)) * Sq * 16 + lg * 4;
  const int* Mbase = mask + b * Sq;

  // prologue: stage tile 0 (both halves) into buffer 0
  {
    *(uint4*)&Klds[0][sr][sc8] = *(const uint4*)Kg;
    *(uint4*)&Klds[0][sr + 32][sc8] = *(const uint4*)(Kg + (size_t)32 * Dq);
    *(uint4*)&Vlds[0][sr][sc8] = *(const uint4*)Vg;
    *(uint4*)&Vlds[0][sr + 32][sc8] = *(const uint4*)(Vg + (size_t)32 * Sq);
  }
  f32x4 oacc[4] = {};
  float lsum[4] = {0.f, 0.f, 0.f, 0.f};
  int cur = 0;
  for (int t = 0; t < Sq / 64; ++t) {
    const int k0 = t * 64;
    __syncthreads();
    // issue independent loads early: next K/V tile + this tile's simi fragments + mask
    uint4 nk0, nk1, nv0, nv1;
    const bool more = (t < Sq / 64 - 1);
    if (more) {
      nk0 = *(const uint4*)(Kg + (size_t)(k0 + 64) * Dq);
      nk1 = *(const uint4*)(Kg + (size_t)(k0 + 96) * Dq);
      nv0 = *(const uint4*)(Vg + (k0 + 64));
      nv1 = *(const uint4*)(Vg + (size_t)32 * Sq + (k0 + 64));
    }
    ushort4 sv4[4];
    float ma[4];
#pragma unroll
    for (int ng = 0; ng < 4; ++ng) {
      int kk = k0 + ng * 16 + l15;
      sv4[ng] = *(const ushort4*)&sB[(size_t)kk * 16];
      ma[ng] = ((float)Mbase[kk] - 1.0f) * 1e8f;
    }
    // QK^T (Q pre-scaled by 1/8 via Wq)
    f32x4 sc[4] = {};
#pragma unroll
    for (int ng = 0; ng < 4; ++ng) {
      short8 bk0 = *(const short8*)&Klds[cur][ng * 16 + l15][lg * 8];
      short8 bk1 = *(const short8*)&Klds[cur][ng * 16 + l15][32 + lg * 8];
      sc[ng] = __builtin_amdgcn_mfma_f32_16x16x32_bf16(aq0, bk0, sc[ng], 0, 0, 0);
      sc[ng] = __builtin_amdgcn_mfma_f32_16x16x32_bf16(aq1, bk1, sc[ng], 0, 0, 0);
    }
    // softmax numerator: p = exp(sc * sv * inv + mask_bias)
#pragma unroll
    for (int ng = 0; ng < 4; ++ng) {
#pragma unroll
      for (int rr = 0; rr < 4; ++rr) {
        float sv = bf2f(rr == 0 ? sv4[ng].x : rr == 1 ? sv4[ng].y : rr == 2 ? sv4[ng].z
                                                                            : sv4[ng].w);
        float p = __expf(fmaf(sc[ng][rr] * sv, inv[rr], ma[ng]));
        lsum[rr] += p;
        Plds[wv][lg * 4 + rr][ng * 16 + l15] = f2bf(p);
      }
    }
    // P reload (per-wave LDS region; wave-internal ordering via lgkmcnt)
    short8 pa0 = *(const short8*)&Plds[wv][l15][lg * 8];
    short8 pa1 = *(const short8*)&Plds[wv][l15][32 + lg * 8];
#pragma unroll
    for (int dg = 0; dg < 4; ++dg) {
      short8 bv0 = *(const short8*)&Vlds[cur][dg * 16 + l15][lg * 8];
      short8 bv1 = *(const short8*)&Vlds[cur][dg * 16 + l15][32 + lg * 8];
      oacc[dg] = __builtin_amdgcn_mfma_f32_16x16x32_bf16(pa0, bv0, oacc[dg], 0, 0, 0);
      oacc[dg] = __builtin_amdgcn_mfma_f32_16x16x32_bf16(pa1, bv1, oacc[dg], 0, 0, 0);
    }
    // write next tile into the other buffer
    if (more) {
      *(uint4*)&Klds[cur ^ 1][sr][sc8] = nk0;
      *(uint4*)&Klds[cur ^ 1][sr + 32][sc8] = nk1;
      *(uint4*)&Vlds[cur ^ 1][sr][sc8] = nv0;
      *(uint4*)&Vlds[cur ^ 1][sr + 32][sc8] = nv1;
      cur ^= 1;
    }
  }
#pragma unroll
  for (int rr = 0; rr < 4; ++rr)
    for (int m = 1; m < 16; m <<= 1) lsum[rr] += __shfl_xor(lsum[rr], m, 64);
#pragma unroll
  for (int dg = 0; dg < 4; ++dg)
    for (int rr = 0; rr < 4; ++rr) {
      int qg = qw + lg * 4 + rr;
      O[((size_t)(b * Sq + qg)) * Dq + h * HDq + dg * 16 + l15] = f2bf(oacc[dg][rr] / lsum[rr]);
    }
}

// ---------------- LayerNorm in-place on d_out ----------------
__global__ __launch_bounds__(256) void lnorm(float* __restrict__ X,
                                             const float* __restrict__ gamma,
                                             const float* __restrict__ beta) {
  const int tid = threadIdx.x, lane = tid & 63, wv = tid >> 6;
  const int row = blockIdx.x * 4 + wv;
  float* xr = X + (size_t)row * Dq + lane * 8;
  float4 x0 = *(float4*)xr;
  float4 x1 = *(float4*)(xr + 4);
  float s = x0.x + x0.y + x0.z + x0.w + x1.x + x1.y + x1.z + x1.w;
  float s2 = x0.x * x0.x + x0.y * x0.y + x0.z * x0.z + x0.w * x0.w +
             x1.x * x1.x + x1.y * x1.y + x1.z * x1.z + x1.w * x1.w;
  for (int m = 1; m < 64; m <<= 1) {
    s += __shfl_xor(s, m, 64);
    s2 += __shfl_xor(s2, m, 64);
  }
  float mu = s * (1.0f / 512.0f);
  float var = s2 * (1.0f / 512.0f) - mu * mu;
  float rstd = rsqrtf(var + 1e-5f);
  const float* g = gamma + lane * 8;
  const float* be = beta + lane * 8;
  float4 y0, y1;
  y0.x = (x0.x - mu) * rstd * g[0] + be[0];
  y0.y = (x0.y - mu) * rstd * g[1] + be[1];
  y0.z = (x0.z - mu) * rstd * g[2] + be[2];
  y0.w = (x0.w - mu) * rstd * g[3] + be[3];
  y1.x = (x1.x - mu) * rstd * g[4] + be[4];
  y1.y = (x1.y - mu) * rstd * g[5] + be[5];
  y1.z = (x1.z - mu) * rstd * g[6] + be[6];
  y1.w = (x1.w - mu) * rstd * g[7] + be[7];
  *(float4*)xr = y0;
  *(float4*)(xr + 4) = y1;
}

extern "C" void kernel_launch(void* const* d_in, const int* in_sizes, int n_in,
                              void* d_out, int out_size, void* d_ws, size_t ws_size,
                              hipStream_t stream) {
  const float* query = (const float*)d_in[0];
  const float* key = (const float*)d_in[1];
  const float* value = (const float*)d_in[2];
  const float* qpe = (const float*)d_in[3];
  const float* kpe = (const float*)d_in[4];
  const int* mask = (const int*)d_in[5];
  const float* Wq = (const float*)d_in[6];
  const float* Wk = (const float*)d_in[7];
  const float* Wv = (const float*)d_in[8];
  const float* Wo = (const float*)d_in[9];
  const float* gamma = (const float*)d_in[10];
  const float* beta = (const float*)d_in[11];
  float* out = (float*)d_out;

  char* ws = (char*)d_ws;
  size_t off = 0;
  unsigned short* Qb = (unsigned short*)(ws + off); off += (size_t)Bq * Sq * Dq * 2;    // 8MB
  unsigned short* Kb = (unsigned short*)(ws + off); off += (size_t)Bq * Sq * Dq * 2;    // 8MB
  unsigned short* VbT = (unsigned short*)(ws + off); off += (size_t)Bq * Sq * Dq * 2;   // 8MB
  unsigned short* Wqt = (unsigned short*)(ws + off); off += (size_t)Dq * Dq * 2;
  unsigned short* Wkt = (unsigned short*)(ws + off); off += (size_t)Dq * Dq * 2;
  unsigned short* Wvt = (unsigned short*)(ws + off); off += (size_t)Dq * Dq * 2;
  unsigned short* Wot = (unsigned short*)(ws + off); off += (size_t)Dq * Dq * 2;
  unsigned short* simiB = (unsigned short*)(ws + off); off += (size_t)Bq * Sq * Sq * 2; // 32MB
  float* invsum = (float*)(ws + off); off += (size_t)Bq * Sq * 4;
  unsigned short* Ob = (unsigned short*)(ws + off); off += (size_t)Bq * Sq * Dq * 2;    // 8MB
  unsigned short* qpeb = (unsigned short*)(ws + off); off += (size_t)Bq * Sq * Pq * 2;  // 1MB
  unsigned short* kpeb = (unsigned short*)(ws + off); off += (size_t)Bq * Sq * Pq * 2;  // 1MB

  dim3 blk(256);
  convW<<<dim3(16, 16), blk, 0, stream>>>(Wq, Wqt, 0.125f);  // fold 1/sqrt(HD) into Wq
  convW<<<dim3(16, 16), blk, 0, stream>>>(Wk, Wkt, 1.0f);
  convW<<<dim3(16, 16), blk, 0, stream>>>(Wv, Wvt, 1.0f);
  convW<<<dim3(16, 16), blk, 0, stream>>>(Wo, Wot, 1.0f);
  cvtbf<<<dim3(Bq * Sq * Pq / 8 / 256), blk, 0, stream>>>(qpe, qpeb, Bq * Sq * Pq / 8);
  cvtbf<<<dim3(Bq * Sq * Pq / 8 / 256), blk, 0, stream>>>(kpe, kpeb, Bq * Sq * Pq / 8);
  possim<<<dim3(Sq / 16, Bq), blk, 0, stream>>>(qpeb, kpeb, simiB, invsum);
  gemm512<true, 0, false><<<dim3(128, 8), blk, 0, stream>>>(query, Wqt, Qb, nullptr, nullptr);
  gemm512<true, 0, false><<<dim3(128, 8), blk, 0, stream>>>(key, Wkt, Kb, nullptr, nullptr);
  gemm512<true, 0, true><<<dim3(128, 8), blk, 0, stream>>>(value, Wvt, VbT, nullptr, nullptr);
  attn<<<dim3(Sq / 64, Hq, Bq), blk, 0, stream>>>(Qb, Kb, VbT, simiB, invsum, mask, Ob);
  gemm512<false, 1, false><<<dim3(128, 8), blk, 0, stream>>>(Ob, Wot, nullptr, query, out);
  lnorm<<<dim3(Bq * Sq / 4), blk, 0, stream>>>(out, gamma, beta);
}